// Round 1
// baseline (385.723 us; speedup 1.0000x reference)
//
#include <hip/hip_runtime.h>

// EGAttention: B=4,H=128,W=128,C=256,NH=8,HD=32. 512 windows x 8 heads.
// qkv fp32 (3,B,HW,C); res fp32 (B,HW,C); out fp32 (B,HW,C).
// Pass A: per (w,n) tile: QK^T (MFMA bf16), +bias, row-norm, P=1-cos, x_u=P@V -> out,
//         and atomicAdd per-window sum(|attn|).
// Pass B: M_w = max(sum_w / max_w, 0.5).
// Pass C: out = x_u*M + res*(1-M)  (elementwise, float4).

typedef __attribute__((ext_vector_type(8))) short bf16x8;
typedef __attribute__((ext_vector_type(4))) float f32x4;

#define PI_F 3.14159265358979323846f

__device__ __forceinline__ short f2bf(float f) {
    union { float f; unsigned u; } v; v.f = f;
    unsigned r = v.u + 0x7fffu + ((v.u >> 16) & 1u);   // RNE bf16 (inputs finite)
    return (short)(r >> 16);
}

__device__ __forceinline__ bf16x8 load_frag8(const float* __restrict__ p) {
    float4 x0 = *(const float4*)p;
    float4 x1 = *(const float4*)(p + 4);
    bf16x8 r;
    r[0] = f2bf(x0.x); r[1] = f2bf(x0.y); r[2] = f2bf(x0.z); r[3] = f2bf(x0.w);
    r[4] = f2bf(x1.x); r[5] = f2bf(x1.y); r[6] = f2bf(x1.z); r[7] = f2bf(x1.w);
    return r;
}

__global__ __launch_bounds__(256, 3) void eg_attn_main(
    const float* __restrict__ q, const float* __restrict__ k,
    const float* __restrict__ v, float* __restrict__ out,
    float* __restrict__ wsum)
{
    const int bx = blockIdx.x;
    const int w = bx >> 3;          // window (0..511)
    const int n = bx & 7;           // head
    const int t = threadIdx.x;
    const int lane = t & 63, wv = t >> 6;
    const int quad = lane >> 4, l15 = lane & 15;

    __shared__ float gd[256];                       // bias(j-i): 2*sin(d*pi/127)
    __shared__ __align__(16) short pbuf[128 * 136]; // P bf16, pad 136 to dodge conflicts
    __shared__ __align__(16) short vtbuf[32 * 136]; // V^T bf16 [d][j]
    __shared__ float redsum[4];

    if (t < 255) gd[t] = 2.0f * sinf((float)(t - 127) * (PI_F / 127.0f));

    // stage V^T (bf16) into LDS: thread t -> row j=t&127, d-range (t>>7)*16..+15
    {
        const int j = t & 127, dq = t >> 7;
        const float* vp = v + (size_t)(w * 128 + j) * 256 + n * 32 + dq * 16;
        float4 a0 = ((const float4*)vp)[0];
        float4 a1 = ((const float4*)vp)[1];
        float4 a2 = ((const float4*)vp)[2];
        float4 a3 = ((const float4*)vp)[3];
        float tmp[16] = {a0.x, a0.y, a0.z, a0.w, a1.x, a1.y, a1.z, a1.w,
                         a2.x, a2.y, a2.z, a2.w, a3.x, a3.y, a3.z, a3.w};
#pragma unroll
        for (int e = 0; e < 16; e++)
            vtbuf[(dq * 16 + e) * 136 + j] = f2bf(tmp[e]);
    }

    // ---- QK^T: wave wv owns rows m0..m0+31, all 128 cols. K=32 = one MFMA. ----
    const int m0 = wv * 32;
    const float* qb = q + (size_t)(w * 128) * 256 + n * 32;
    const float* kb = k + (size_t)(w * 128) * 256 + n * 32;

    bf16x8 aq[2], bk[8];
#pragma unroll
    for (int ti = 0; ti < 2; ti++)
        aq[ti] = load_frag8(qb + (m0 + ti * 16 + l15) * 256 + quad * 8);
#pragma unroll
    for (int tj = 0; tj < 8; tj++)
        bk[tj] = load_frag8(kb + (tj * 16 + l15) * 256 + quad * 8);

    f32x4 acc[2][8];
#pragma unroll
    for (int ti = 0; ti < 2; ti++)
#pragma unroll
        for (int tj = 0; tj < 8; tj++) {
            f32x4 z = {0.f, 0.f, 0.f, 0.f};
            acc[ti][tj] = z;
        }
#pragma unroll
    for (int ti = 0; ti < 2; ti++)
#pragma unroll
        for (int tj = 0; tj < 8; tj++)
            acc[ti][tj] = __builtin_amdgcn_mfma_f32_16x16x32_bf16(
                aq[ti], bk[tj], acc[ti][tj], 0, 0, 0);

    __syncthreads();   // gd + vtbuf ready

    // ---- bias, |attn| sum, row norms, P = 1 - cos(attn/norm * pi/2) ----
    const float cb = 0.1f * sinf((float)(w & 127) * (PI_F / 128.0f));
    float lsum = 0.f;

#pragma unroll
    for (int ti = 0; ti < 2; ti++) {
#pragma unroll
        for (int r = 0; r < 4; r++) {
            const int i = m0 + ti * 16 + quad * 4 + r;   // C-layout row
            float a[8];
            float ss = 0.f;
#pragma unroll
            for (int tj = 0; tj < 8; tj++) {
                const int j = tj * 16 + l15;             // C-layout col
                float val = acc[ti][tj][r] + cb * gd[j - i + 127];
                a[tj] = val;
                ss += val * val;
                lsum += fabsf(val);
            }
            // row sum-of-squares: reduce across the 16 lanes of this quad
            ss += __shfl_xor(ss, 1);
            ss += __shfl_xor(ss, 2);
            ss += __shfl_xor(ss, 4);
            ss += __shfl_xor(ss, 8);
            const float rs = 1.57079632679f / fmaxf(sqrtf(ss), 1e-12f);
#pragma unroll
            for (int tj = 0; tj < 8; tj++) {
                float pv = 1.0f - __cosf(a[tj] * rs);    // arg in [-pi/2,pi/2]
                pbuf[i * 136 + tj * 16 + l15] = f2bf(pv);
            }
        }
    }

    // per-window |attn| sum -> atomic
#pragma unroll
    for (int mask = 1; mask < 64; mask <<= 1) lsum += __shfl_xor(lsum, mask);
    if (lane == 0) redsum[wv] = lsum;
    __syncthreads();   // also guards pbuf write->read
    if (t == 0) atomicAdd(wsum + w, redsum[0] + redsum[1] + redsum[2] + redsum[3]);

    // ---- x_u = P @ V : M=i(128 rows, wave owns 32), N=d(32), K=j(128 -> 4 steps) ----
    bf16x8 vfr[2][4];
#pragma unroll
    for (int tn = 0; tn < 2; tn++)
#pragma unroll
        for (int kk = 0; kk < 4; kk++)
            vfr[tn][kk] = *(const bf16x8*)&vtbuf[(tn * 16 + l15) * 136 + kk * 32 + quad * 8];

    f32x4 xacc[2][2];
#pragma unroll
    for (int ti = 0; ti < 2; ti++)
#pragma unroll
        for (int tn = 0; tn < 2; tn++) {
            f32x4 z = {0.f, 0.f, 0.f, 0.f};
            xacc[ti][tn] = z;
        }
#pragma unroll
    for (int ti = 0; ti < 2; ti++)
#pragma unroll
        for (int kk = 0; kk < 4; kk++) {
            bf16x8 pa = *(const bf16x8*)&pbuf[(m0 + ti * 16 + l15) * 136 + kk * 32 + quad * 8];
#pragma unroll
            for (int tn = 0; tn < 2; tn++)
                xacc[ti][tn] = __builtin_amdgcn_mfma_f32_16x16x32_bf16(
                    pa, vfr[tn][kk], xacc[ti][tn], 0, 0, 0);
        }

    // store ungated x_u
    float* ob = out + (size_t)(w * 128) * 256 + n * 32;
#pragma unroll
    for (int ti = 0; ti < 2; ti++)
#pragma unroll
        for (int tn = 0; tn < 2; tn++)
#pragma unroll
            for (int r = 0; r < 4; r++) {
                const int i = m0 + ti * 16 + quad * 4 + r;
                ob[i * 256 + tn * 16 + l15] = xacc[ti][tn][r];
            }
}

// 512 window sums -> M_w = max(s/smax, 0.5)
__global__ __launch_bounds__(512) void eg_gate(const float* __restrict__ wsum,
                                               float* __restrict__ M)
{
    const int t = threadIdx.x;   // 512 threads
    __shared__ float red[8];
    const float s = wsum[t];
    float m = s;
#pragma unroll
    for (int mask = 1; mask < 64; mask <<= 1) m = fmaxf(m, __shfl_xor(m, mask));
    if ((t & 63) == 0) red[t >> 6] = m;
    __syncthreads();
    if (t == 0) {
        float mm = red[0];
#pragma unroll
        for (int i = 1; i < 8; i++) mm = fmaxf(mm, red[i]);
        red[0] = mm;
    }
    __syncthreads();
    M[t] = fmaxf(s / red[0], 0.5f);
}

// out = x_u * M + res * (1 - M)
__global__ __launch_bounds__(256) void eg_finalize(float* __restrict__ out,
                                                   const float* __restrict__ res,
                                                   const float* __restrict__ M)
{
    const int tid = blockIdx.x * 256 + threadIdx.x;   // 4194304 float4s
    const float Mw = M[tid >> 13];                    // window = (tid*4)>>15
    const float om = 1.0f - Mw;
    float4 x = ((const float4*)out)[tid];
    float4 r = ((const float4*)res)[tid];
    x.x = x.x * Mw + r.x * om;
    x.y = x.y * Mw + r.y * om;
    x.z = x.z * Mw + r.z * om;
    x.w = x.w * Mw + r.w * om;
    ((float4*)out)[tid] = x;
}

extern "C" void kernel_launch(void* const* d_in, const int* in_sizes, int n_in,
                              void* d_out, int out_size, void* d_ws, size_t ws_size,
                              hipStream_t stream) {
    const float* qkv = (const float*)d_in[0];
    const float* res = (const float*)d_in[1];
    const long plane = 16777216L;               // B*HW*C
    const float* q = qkv;
    const float* k = qkv + plane;
    const float* v = qkv + 2 * plane;
    float* out = (float*)d_out;

    float* wsum = (float*)d_ws;                 // 512 floats
    float* M = wsum + 512;                      // 512 floats

    hipMemsetAsync(wsum, 0, 512 * sizeof(float), stream);
    eg_attn_main<<<4096, 256, 0, stream>>>(q, k, v, out, wsum);
    eg_gate<<<1, 512, 0, stream>>>(wsum, M);
    eg_finalize<<<16384, 256, 0, stream>>>(out, res, M);
}